// Round 1
// baseline (113.839 us; speedup 1.0000x reference)
//
#include <hip/hip_runtime.h>
#include <math.h>

// FrequencyMaskingLoss — psychoacoustic masking loss (forward only, scalar out).
// Pipeline: [K1] STFT(ref & delta via one complex FFT) + per-frame PSD + frame max
//           [K2] global psd_max   [K3] per-frame masking threshold + loss partial
//           [K4] mean -> out[0]
// WINDOW=512, HOP=128, F=257, n_frames=(L-512)/128+1 (=1247 for L=160000).

#define FBINS 257

// ---------------------------------------------------------------- kernel 1
__global__ __launch_bounds__(128) void k1_stft(
    const float* __restrict__ xadv, const float* __restrict__ xref,
    float* __restrict__ psd_db, float* __restrict__ pd, float* __restrict__ fmaxs)
{
    __shared__ float re[512], im[512], twr[256], twi[256];
    __shared__ float wmax[2];
    const int t = blockIdx.x, tid = threadIdx.x;
    const double TWO_PI = 6.283185307179586476925286766559;

    // twiddles e^{-2pi i j/512}
    for (int j = tid; j < 256; j += 128) {
        double s, c;
        sincos(-(TWO_PI / 512.0) * (double)j, &s, &c);
        twr[j] = (float)c; twi[j] = (float)s;
    }
    // load + hann window + bit-reverse; z = w*ref + i*w*delta
    const int base_idx = t * 128;
    for (int n = tid; n < 512; n += 128) {
        double cw = cos((TWO_PI * (double)n) / 512.0);
        float  w  = (float)(0.5 * (1.0 - cw));
        float  r  = xref[base_idx + n];
        float  a  = xadv[base_idx + n];
        int    p  = __brev((unsigned)n) >> 23;   // 9-bit reversal
        re[p] = w * r;
        im[p] = w * (a - r);
    }
    __syncthreads();

    // 9-stage radix-2 DIT
    for (int stage = 1; stage <= 9; ++stage) {
        int half  = 1 << (stage - 1);
        int tstep = 512 >> stage;
        for (int b = tid; b < 256; b += 128) {
            int j    = b & (half - 1);
            int base = ((b >> (stage - 1)) << stage) + j;
            float wr = twr[j * tstep], wi = twi[j * tstep];
            float vr0 = re[base + half], vi0 = im[base + half];
            float vr = vr0 * wr - vi0 * wi;
            float vi = vr0 * wi + vi0 * wr;
            float ur = re[base], ui = im[base];
            re[base]        = ur + vr; im[base]        = ui + vi;
            re[base + half] = ur - vr; im[base + half] = ui - vi;
        }
        __syncthreads();
    }

    // unpack A=rfft(ref frame), B=rfft(delta frame); PSDs
    const float S2 = 1.0172526041666667e-05f;   // (sqrt(8/3)/512)^2
    float lmax = -1e30f;
    for (int k = tid; k <= 256; k += 128) {
        int nk = (512 - k) & 511;
        float zr = re[k],  zi = im[k];
        float yr = re[nk], yi = im[nk];
        float ar = 0.5f * (zr + yr), ai = 0.5f * (zi - yi);   // ref spectrum
        float br = 0.5f * (zi + yi), bi = 0.5f * (yr - zr);   // delta spectrum
        float prefp = S2 * (ar * ar + ai * ai);
        float pdb   = 10.0f * log10f(prefp);
        pdb = fmaxf(pdb, -200.0f);
        psd_db[t * FBINS + k] = pdb;
        pd[t * FBINS + k]     = S2 * (br * br + bi * bi);
        lmax = fmaxf(lmax, pdb);
    }
    for (int off = 32; off > 0; off >>= 1) lmax = fmaxf(lmax, __shfl_down(lmax, off));
    if ((tid & 63) == 0) wmax[tid >> 6] = lmax;
    __syncthreads();
    if (tid == 0) fmaxs[t] = fmaxf(wmax[0], wmax[1]);
}

// ---------------------------------------------------------------- kernel 2
__global__ __launch_bounds__(256) void k2_max(
    const float* __restrict__ fmaxs, int nf, float* __restrict__ psdmax)
{
    __shared__ float sm[4];
    float v = -1e30f;
    for (int i = threadIdx.x; i < nf; i += 256) v = fmaxf(v, fmaxs[i]);
    for (int off = 32; off > 0; off >>= 1) v = fmaxf(v, __shfl_down(v, off));
    if ((threadIdx.x & 63) == 0) sm[threadIdx.x >> 6] = v;
    __syncthreads();
    if (threadIdx.x == 0)
        psdmax[0] = fmaxf(fmaxf(sm[0], sm[1]), fmaxf(sm[2], sm[3]));
}

// ---------------------------------------------------------------- kernel 3
__global__ __launch_bounds__(256) void k3_threshold(
    const float* __restrict__ psd_db, const float* __restrict__ pd,
    const float* __restrict__ psdmax, float* __restrict__ floss)
{
    __shared__ float barkf[FBINS], athdb[FBINS], athp[FBINS];
    __shared__ float p_s[FBINS], pw_s[FBINS], m_s[FBINS];
    __shared__ float mc_s[FBINS], shift_s[FBINS], barkm_s[FBINS], ups_s[FBINS];
    __shared__ int   val_s[FBINS], keep_s[FBINS], bin_s[FBINS];
    __shared__ int   nk_sh;
    __shared__ float red[4];

    const int t = blockIdx.x, tid = threadIdx.x;
    const float pmax   = psdmax[0];
    const float shift0 = 96.0f - pmax;

    // constant tables (double, cast f32 — matches numpy f64->f32) + load frame PSD
    for (int f = tid; f < FBINS; f += 256) {
        double freq = 31.25 * (double)f;            // SR/2 / 256 * f, exact
        double q    = freq / 7500.0;
        double bd   = 13.0 * atan(0.00076 * freq) + 3.5 * atan(q * q);
        float  bf   = (float)bd;
        barkf[f] = bf;
        float av;
        if (f == 0) { av = -INFINITY; athp[f] = 0.0f; }
        else {
            double fk = freq * 0.001;
            double ad = 3.64 * pow(fk, -0.8)
                      - 6.5 * exp(-0.6 * (fk - 3.3) * (fk - 3.3))
                      + 0.001 * fk * fk * fk * fk - 12.0;
            av = (float)ad;
            athp[f] = exp10f(av / 10.0f);
        }
        athdb[f] = av;
        float pv = shift0 + psd_db[t * FBINS + f];
        p_s[f]  = pv;
        pw_s[f] = exp10f(pv / 10.0f);
    }
    __syncthreads();

    // local-max detection + tonal masker level
    for (int f = tid; f < FBINS; f += 256) {
        int v = 0; float m = -1e30f;
        if (f >= 1 && f <= 255) {
            float pc = p_s[f];
            if (pc > p_s[f - 1] && pc > p_s[f + 1]) {
                m = 10.0f * log10f((pw_s[f] + pw_s[f - 1]) + pw_s[f + 1]);
                if (m > athdb[f]) v = 1;
            }
        }
        m_s[f] = m;
        val_s[f] = v;
    }
    __syncthreads();

    // serial part (faithful replication of the reference scan incl. the
    // position-indexed BARK[] access): thread 0 only
    if (tid == 0) {
        int n = 0;
        for (int f = 0; f < FBINS; ++f)
            if (val_s[f]) { bin_s[n] = f; mc_s[n] = m_s[f]; keep_s[n] = 1; ++n; }
        int i_prev = 0;
        for (int i = 1; i < n; ++i) {          // i >= n is inactive: no-op
            bool close        = (barkf[i] - barkf[i_prev]) < 0.5f;  // positions!
            bool prev_smaller = mc_s[i_prev] < mc_s[i];
            if (close) {
                keep_s[prev_smaller ? i_prev : i] = 0;
                if (prev_smaller) i_prev = i_prev + 1;
            } else {
                i_prev = i;
            }
        }
        int nk = 0;
        for (int k = 0; k < n; ++k) {
            if (keep_s[k]) {
                int   f   = bin_s[k];
                float mc  = mc_s[k];
                float dsh = -6.025f - 0.275f * barkf[f];
                shift_s[nk] = mc + dsh;
                barkm_s[nk] = barkf[f];
                ups_s[nk]   = -27.0f + 0.37f * fmaxf(mc - 40.0f, 0.0f);
                ++nk;
            }
        }
        nk_sh = nk;
    }
    __syncthreads();

    // per-bin threshold power + loss term  (thr kept in POWER domain:
    // 10^(10*log10(X)/10) == X, so skip the log/exp round-trip)
    const int   nk = nk_sh;
    const float C  = 3981071705.534973f / exp10f(pmax / 10.0f);  // 10^9.6 / 10^(pmax/10)
    float lsum = 0.0f;
    for (int f = tid; f < FBINS; f += 256) {
        float bf  = barkf[f];
        float acc = 0.0f;
        for (int k = 0; k < nk; ++k) {
            float dz    = bf - barkm_s[k];
            float slope = (dz > 0.0f) ? ups_s[k] : 27.0f;
            float tdb   = shift_s[k] + slope * dz;
            acc += exp10f(tdb / 10.0f);
        }
        float thrpow = acc + athp[f];
        float pds    = C * pd[t * FBINS + f];
        lsum += fmaxf(pds - thrpow, 0.0f);
    }
    for (int off = 32; off > 0; off >>= 1) lsum += __shfl_down(lsum, off);
    if ((tid & 63) == 0) red[tid >> 6] = lsum;
    __syncthreads();
    if (tid == 0) floss[t] = (red[0] + red[1]) + (red[2] + red[3]);
}

// ---------------------------------------------------------------- kernel 4
__global__ __launch_bounds__(256) void k4_final(
    const float* __restrict__ floss, int nf, float* __restrict__ out)
{
    __shared__ float red[4];
    float s = 0.0f;
    for (int i = threadIdx.x; i < nf; i += 256) s += floss[i];
    for (int off = 32; off > 0; off >>= 1) s += __shfl_down(s, off);
    if ((threadIdx.x & 63) == 0) red[threadIdx.x >> 6] = s;
    __syncthreads();
    if (threadIdx.x == 0) {
        float total = (red[0] + red[1]) + (red[2] + red[3]);
        out[0] = 1e-6f * (total / (float)(nf * FBINS));
    }
}

// ---------------------------------------------------------------- launch
extern "C" void kernel_launch(void* const* d_in, const int* in_sizes, int n_in,
                              void* d_out, int out_size, void* d_ws, size_t ws_size,
                              hipStream_t stream)
{
    const float* x_adv = (const float*)d_in[0];
    const float* x_ref = (const float*)d_in[1];
    float*       out   = (float*)d_out;

    const int L  = in_sizes[0];
    const int nf = (L - 512) / 128 + 1;           // 1247 for L=160000

    // workspace layout (floats)
    float* ws      = (float*)d_ws;
    float* psd_db  = ws;                          // nf*257
    float* pd      = ws + (size_t)nf * FBINS;     // nf*257
    float* fmaxs   = ws + (size_t)2 * nf * FBINS; // nf
    float* floss   = fmaxs + nf;                  // nf
    float* psdmax  = floss + nf;                  // 1

    k1_stft     <<<nf, 128, 0, stream>>>(x_adv, x_ref, psd_db, pd, fmaxs);
    k2_max      <<<1,  256, 0, stream>>>(fmaxs, nf, psdmax);
    k3_threshold<<<nf, 256, 0, stream>>>(psd_db, pd, psdmax, floss);
    k4_final    <<<1,  256, 0, stream>>>(floss, nf, out);
}

// Round 2
// 93.869 us; speedup vs baseline: 1.2127x; 1.2127x over previous
//
#include <hip/hip_runtime.h>
#include <math.h>

// FrequencyMaskingLoss — psychoacoustic masking loss (forward only, scalar out).
// Pipeline: [K0] init constant tables (f64 math, once per call)
//           [K1] STFT(ref & delta via one complex FFT) + per-frame PSD + frame max
//           [K2] global psd_max   [K3] per-frame masking threshold + loss partial
//           [K4] mean -> out[0]
// WINDOW=512, HOP=128, F=257, n_frames=(L-512)/128+1 (=1247 for L=160000).

#define FBINS 257

// table layout inside ws (floats): barkf[257] | athdb[257] | athp[257] |
//                                  hann[512] | twr[256] | twi[256]   (= 1795)
#define TAB_BARK  0
#define TAB_ATHDB 257
#define TAB_ATHP  514
#define TAB_HANN  771
#define TAB_TWR   1283
#define TAB_TWI   1539
#define TAB_FLOATS 2048   // padded

// ---------------------------------------------------------------- kernel 0
// One block. All double-precision table math lives here (frame-invariant).
__global__ __launch_bounds__(256) void k0_init(float* __restrict__ tab)
{
    const int tid = threadIdx.x;
    const double TWO_PI = 6.283185307179586476925286766559;
    for (int f = tid; f < FBINS; f += 256) {
        double freq = 31.25 * (double)f;            // SR/2/256 * f, exact
        double q    = freq / 7500.0;
        tab[TAB_BARK + f] = (float)(13.0 * atan(0.00076 * freq) + 3.5 * atan(q * q));
        if (f == 0) {
            tab[TAB_ATHDB] = -INFINITY;
            tab[TAB_ATHP]  = 0.0f;
        } else {
            double fk = freq * 0.001;
            double ad = 3.64 * pow(fk, -0.8)
                      - 6.5 * exp(-0.6 * (fk - 3.3) * (fk - 3.3))
                      + 0.001 * fk * fk * fk * fk - 12.0;
            float av = (float)ad;
            tab[TAB_ATHDB + f] = av;
            tab[TAB_ATHP  + f] = exp10f(av / 10.0f);
        }
    }
    for (int n = tid; n < 512; n += 256) {
        double cw = cos((TWO_PI * (double)n) / 512.0);
        tab[TAB_HANN + n] = (float)(0.5 * (1.0 - cw));
    }
    for (int j = tid; j < 256; j += 256) {
        double s, c;
        sincos(-(TWO_PI / 512.0) * (double)j, &s, &c);
        tab[TAB_TWR + j] = (float)c;
        tab[TAB_TWI + j] = (float)s;
    }
}

// ---------------------------------------------------------------- kernel 1
// One frame per block; z = hann*ref + i*hann*delta -> one 512-pt complex FFT.
__global__ __launch_bounds__(256) void k1_stft(
    const float* __restrict__ xadv, const float* __restrict__ xref,
    const float* __restrict__ tab,
    float* __restrict__ psd_db, float* __restrict__ pd, float* __restrict__ fmaxs)
{
    __shared__ float re[512], im[512], twr[256], twi[256];
    __shared__ float wmax[4];
    const int t = blockIdx.x, tid = threadIdx.x;

    twr[tid] = tab[TAB_TWR + tid];
    twi[tid] = tab[TAB_TWI + tid];

    const int base_idx = t * 128;
    for (int n = tid; n < 512; n += 256) {
        float w = tab[TAB_HANN + n];
        float r = xref[base_idx + n];
        float a = xadv[base_idx + n];
        int   p = __brev((unsigned)n) >> 23;   // 9-bit reversal
        re[p] = w * r;
        im[p] = w * (a - r);
    }
    __syncthreads();

    // 9-stage radix-2 DIT, one butterfly per thread per stage
    for (int stage = 1; stage <= 9; ++stage) {
        int half  = 1 << (stage - 1);
        int tstep = 512 >> stage;
        int j     = tid & (half - 1);
        int base  = ((tid >> (stage - 1)) << stage) + j;
        float wr = twr[j * tstep], wi = twi[j * tstep];
        float vr0 = re[base + half], vi0 = im[base + half];
        float vr = vr0 * wr - vi0 * wi;
        float vi = vr0 * wi + vi0 * wr;
        float ur = re[base], ui = im[base];
        __syncthreads();   // reads done before writes of this stage
        re[base]        = ur + vr; im[base]        = ui + vi;
        re[base + half] = ur - vr; im[base + half] = ui - vi;
        __syncthreads();
    }

    // unpack A=rfft(ref), B=rfft(delta); PSDs
    const float S2 = 1.0172526041666667e-05f;   // (sqrt(8/3)/512)^2
    float lmax = -1e30f;
    for (int k = tid; k <= 256; k += 256) {
        int nk = (512 - k) & 511;
        float zr = re[k],  zi = im[k];
        float yr = re[nk], yi = im[nk];
        float ar = 0.5f * (zr + yr), ai = 0.5f * (zi - yi);   // ref spectrum
        float br = 0.5f * (zi + yi), bi = 0.5f * (yr - zr);   // delta spectrum
        float prefp = S2 * (ar * ar + ai * ai);
        float pdb   = fmaxf(10.0f * log10f(prefp), -200.0f);
        psd_db[t * FBINS + k] = pdb;
        pd[t * FBINS + k]     = S2 * (br * br + bi * bi);
        lmax = fmaxf(lmax, pdb);
    }
    for (int off = 32; off > 0; off >>= 1) lmax = fmaxf(lmax, __shfl_down(lmax, off));
    if ((tid & 63) == 0) wmax[tid >> 6] = lmax;
    __syncthreads();
    if (tid == 0)
        fmaxs[t] = fmaxf(fmaxf(wmax[0], wmax[1]), fmaxf(wmax[2], wmax[3]));
}

// ---------------------------------------------------------------- kernel 2
__global__ __launch_bounds__(256) void k2_max(
    const float* __restrict__ fmaxs, int nf, float* __restrict__ psdmax)
{
    __shared__ float sm[4];
    float v = -1e30f;
    for (int i = threadIdx.x; i < nf; i += 256) v = fmaxf(v, fmaxs[i]);
    for (int off = 32; off > 0; off >>= 1) v = fmaxf(v, __shfl_down(v, off));
    if ((threadIdx.x & 63) == 0) sm[threadIdx.x >> 6] = v;
    __syncthreads();
    if (threadIdx.x == 0)
        psdmax[0] = fmaxf(fmaxf(sm[0], sm[1]), fmaxf(sm[2], sm[3]));
}

// ---------------------------------------------------------------- kernel 3
__global__ __launch_bounds__(256) void k3_threshold(
    const float* __restrict__ tab,
    const float* __restrict__ psd_db, const float* __restrict__ pd,
    const float* __restrict__ psdmax, float* __restrict__ floss)
{
    __shared__ float barkf[FBINS], athp_s[FBINS];
    __shared__ float p_s[FBINS], pw_s[FBINS];
    __shared__ float mc_s[128], shift_s[128], barkm_s[128], ups_s[128];
    __shared__ int   bin_s[128], keep_s[128];
    __shared__ int   wcnt[4];
    __shared__ float red[4];

    const int t = blockIdx.x, tid = threadIdx.x;
    const int lane = tid & 63, wid = tid >> 6;
    const float pmax   = psdmax[0];
    const float shift0 = 96.0f - pmax;

    // tables from global + frame PSD into LDS
    for (int f = tid; f < FBINS; f += 256) {
        barkf[f]  = tab[TAB_BARK + f];
        athp_s[f] = tab[TAB_ATHP + f];
        float pv = shift0 + psd_db[t * FBINS + f];
        p_s[f]  = pv;
        pw_s[f] = exp10f(pv / 10.0f);
    }
    __syncthreads();

    // local-max + tonal masker level for f = tid (bin 256 can't be interior)
    float m = -1e30f;
    int   pred = 0;
    if (tid >= 1 && tid <= 255) {
        float pc = p_s[tid];
        if (pc > p_s[tid - 1] && pc > p_s[tid + 1]) {
            m = 10.0f * log10f((pw_s[tid] + pw_s[tid - 1]) + pw_s[tid + 1]);
            if (m > tab[TAB_ATHDB + tid]) pred = 1;
        }
    }
    // ballot stream-compaction (stable in frequency order)
    unsigned long long bal = __ballot(pred);
    if (lane == 0) wcnt[wid] = __popcll(bal);
    __syncthreads();
    int base = 0;
    for (int w = 0; w < wid; ++w) base += wcnt[w];
    const int n_total = wcnt[0] + wcnt[1] + wcnt[2] + wcnt[3];
    if (pred) {
        int pos = base + __popcll(bal & ((1ull << lane) - 1));
        bin_s[pos] = tid; mc_s[pos] = m; keep_s[pos] = 1;
    }
    __syncthreads();

    // the inherently-sequential i_prev scan (faithful incl. position-indexed
    // BARK[] access): thread 0, ~n_total iterations
    if (tid == 0) {
        int i_prev = 0;
        for (int i = 1; i < n_total; ++i) {
            bool close        = (barkf[i] - barkf[i_prev]) < 0.5f;  // positions!
            bool prev_smaller = mc_s[i_prev] < mc_s[i];
            if (close) {
                keep_s[prev_smaller ? i_prev : i] = 0;
                if (prev_smaller) i_prev = i_prev + 1;
            } else {
                i_prev = i;
            }
        }
    }
    __syncthreads();

    // compact kept maskers (ballot again), precompute per-masker terms
    int pred2 = (tid < n_total) && keep_s[tid];
    unsigned long long bal2 = __ballot(pred2);
    if (lane == 0) wcnt[wid] = __popcll(bal2);
    __syncthreads();
    int base2 = 0;
    for (int w = 0; w < wid; ++w) base2 += wcnt[w];
    const int nk = wcnt[0] + wcnt[1] + wcnt[2] + wcnt[3];
    if (pred2) {
        int pos = base2 + __popcll(bal2 & ((1ull << lane) - 1));
        int   fb = bin_s[tid];
        float mc = mc_s[tid];
        shift_s[pos] = mc + (-6.025f - 0.275f * barkf[fb]);
        barkm_s[pos] = barkf[fb];
        ups_s[pos]   = -27.0f + 0.37f * fmaxf(mc - 40.0f, 0.0f);
    }
    __syncthreads();

    // per-bin threshold power + loss (threshold kept in POWER domain:
    // 10^(10*log10(X)/10) == X — skip the log/exp round-trip)
    const float C = 3981071705.534973f / exp10f(pmax / 10.0f);  // 10^9.6/10^(pmax/10)
    float lsum = 0.0f;
    for (int f = tid; f < FBINS; f += 256) {
        float bf  = barkf[f];
        float acc = 0.0f;
        for (int k = 0; k < nk; ++k) {
            float dz    = bf - barkm_s[k];
            float slope = (dz > 0.0f) ? ups_s[k] : 27.0f;
            float tdb   = shift_s[k] + slope * dz;
            acc += exp10f(tdb / 10.0f);
        }
        float thrpow = acc + athp_s[f];
        float pds    = C * pd[t * FBINS + f];
        lsum += fmaxf(pds - thrpow, 0.0f);
    }
    for (int off = 32; off > 0; off >>= 1) lsum += __shfl_down(lsum, off);
    if ((tid & 63) == 0) red[tid >> 6] = lsum;
    __syncthreads();
    if (tid == 0) floss[t] = (red[0] + red[1]) + (red[2] + red[3]);
}

// ---------------------------------------------------------------- kernel 4
__global__ __launch_bounds__(256) void k4_final(
    const float* __restrict__ floss, int nf, float* __restrict__ out)
{
    __shared__ float red[4];
    float s = 0.0f;
    for (int i = threadIdx.x; i < nf; i += 256) s += floss[i];
    for (int off = 32; off > 0; off >>= 1) s += __shfl_down(s, off);
    if ((threadIdx.x & 63) == 0) red[threadIdx.x >> 6] = s;
    __syncthreads();
    if (threadIdx.x == 0) {
        float total = (red[0] + red[1]) + (red[2] + red[3]);
        out[0] = 1e-6f * (total / (float)(nf * FBINS));
    }
}

// ---------------------------------------------------------------- launch
extern "C" void kernel_launch(void* const* d_in, const int* in_sizes, int n_in,
                              void* d_out, int out_size, void* d_ws, size_t ws_size,
                              hipStream_t stream)
{
    const float* x_adv = (const float*)d_in[0];
    const float* x_ref = (const float*)d_in[1];
    float*       out   = (float*)d_out;

    const int L  = in_sizes[0];
    const int nf = (L - 512) / 128 + 1;           // 1247 for L=160000

    // workspace layout (floats)
    float* ws      = (float*)d_ws;
    float* tab     = ws;                                   // TAB_FLOATS
    float* psd_db  = ws + TAB_FLOATS;                      // nf*257
    float* pd      = psd_db + (size_t)nf * FBINS;          // nf*257
    float* fmaxs   = pd + (size_t)nf * FBINS;              // nf
    float* floss   = fmaxs + nf;                           // nf
    float* psdmax  = floss + nf;                           // 1

    k0_init     <<<1,  256, 0, stream>>>(tab);
    k1_stft     <<<nf, 256, 0, stream>>>(x_adv, x_ref, tab, psd_db, pd, fmaxs);
    k2_max      <<<1,  256, 0, stream>>>(fmaxs, nf, psdmax);
    k3_threshold<<<nf, 256, 0, stream>>>(tab, psd_db, pd, psdmax, floss);
    k4_final    <<<1,  256, 0, stream>>>(floss, nf, out);
}